// Round 4
// baseline (223.215 us; speedup 1.0000x reference)
//
#include <hip/hip_runtime.h>

// Normalized_Graph_expand: out[n, k, :] = feat[g[n,k], :] - feat[n, :]
// B=1, N=25000, F=128, CUT=32.
//
// Chunked multi-pass gather: the 12.8 MB feature table is processed in
// CHUNK_ROWS=5000-row chunks (2.56 MB, fits each XCD's 4 MiB private L2).
// Pass p = blockIdx.y writes only neighbor rows whose index is in chunk p,
// so gather reads become L2-local (each XCD pulls each chunk from L3 once)
// instead of 410 MB of random reads crossing the fabric every kernel.
// Each (n,k) output row is written exactly once (by the pass owning g[n,k]).
//
// - Output stores: nontemporal (never re-read; don't allocate in L2).
// - Index + center loads: nontemporal (streamed once per pass; must not
//   evict the resident chunk from L2).
// - Gather loads: normal (want L2 allocation — that's the whole point).

typedef float f32x4 __attribute__((ext_vector_type(4)));

#define CHUNK_ROWS 5000

__global__ __launch_bounds__(256) void ngx_kernel(
    const float* __restrict__ feat,   // [N, 128]
    const int*   __restrict__ graph,  // [N, 32]
    float*       __restrict__ out,    // [N, 32, 128]
    int N)
{
    const int node = blockIdx.x;
    const int lo   = blockIdx.y * CHUNK_ROWS;   // chunk [lo, lo+CHUNK_ROWS)

    const int tid = threadIdx.x;
    const int c = tid & 31;   // float4 column index within a row
    const int r = tid >> 5;   // base neighbor row (0..7)

    const f32x4 center = __builtin_nontemporal_load(
        reinterpret_cast<const f32x4*>(feat + (size_t)node * 128) + c);

    const int* g = graph + (size_t)node * 32;
    f32x4* o = reinterpret_cast<f32x4*>(out + (size_t)node * 32 * 128);

#pragma unroll
    for (int j = 0; j < 4; ++j) {
        const int nb  = r + j * 8;
        const int idx = __builtin_nontemporal_load(g + nb);  // uniform per 32-lane row
        if ((unsigned)(idx - lo) < (unsigned)CHUNK_ROWS) {
            const f32x4 v =
                reinterpret_cast<const f32x4*>(feat + (size_t)idx * 128)[c];
            __builtin_nontemporal_store(v - center, &o[(size_t)nb * 32 + c]);
        }
    }
}

extern "C" void kernel_launch(void* const* d_in, const int* in_sizes, int n_in,
                              void* d_out, int out_size, void* d_ws, size_t ws_size,
                              hipStream_t stream) {
    const float* feat  = (const float*)d_in[0];
    const int*   graph = (const int*)d_in[1];
    float*       out   = (float*)d_out;

    const int N = in_sizes[1] / 32;          // x_graph is [1, N, 32]
    const int passes = (N + CHUNK_ROWS - 1) / CHUNK_ROWS;

    dim3 grid(N, passes);                    // x fastest -> pass-major execution
    ngx_kernel<<<grid, 256, 0, stream>>>(feat, graph, out, N);
}

// Round 5
// 165.563 us; speedup vs baseline: 1.3482x; 1.3482x over previous
//
#include <hip/hip_runtime.h>

// Normalized_Graph_expand: out[n, k, :] = feat[g[n,k], :] - feat[n, :]
// B=1, N=25000, F=128, CUT=32.
//
// Single-pass XCD-sliced gather. Blocks round-robin across 8 XCDs by linear
// blockIdx [measured m09]. Grid = 4N; block b -> node b>>2, slice b&3; the
// block handles only neighbor rows with idx in slice [s*N/4, (s+1)*N/4).
// XCD = b%8, so each physical XCD consistently processes ONE slice
// (slice s on XCDs s and s+4): per-XCD gather footprint = 3.2 MB < 4 MiB L2
// -> gather reads become L2-resident without multi-pass phasing or sync.
// Union over b covers every (node, row) exactly once, so correctness does
// not depend on the XCD mapping — only locality does.
//
// - Gather loads: normal (want L2 allocation of the slice).
// - Graph + center loads: nontemporal (streamed, 4x-replicated; must not
//   evict the slice from L2; L3-served, latency hidden by occupancy).
// - Output stores: nontemporal (never re-read).

typedef float f32x4 __attribute__((ext_vector_type(4)));

__global__ __launch_bounds__(256) void ngx_kernel(
    const float* __restrict__ feat,   // [N, 128]
    const int*   __restrict__ graph,  // [N, 32]
    float*       __restrict__ out,    // [N, 32, 128]
    int N)
{
    const int b     = blockIdx.x;
    const int node  = b >> 2;
    const int slice = b & 3;
    const int lo = (int)(((long long)slice * N) >> 2);        // N/4 boundaries
    const int hi = (int)(((long long)(slice + 1) * N) >> 2);

    const int tid = threadIdx.x;
    const int c = tid & 31;   // float4 column index within a row
    const int r = tid >> 5;   // base neighbor row (0..7)

    const f32x4 center = __builtin_nontemporal_load(
        reinterpret_cast<const f32x4*>(feat + (size_t)node * 128) + c);

    const int* g = graph + (size_t)node * 32;
    f32x4* o = reinterpret_cast<f32x4*>(out + (size_t)node * 32 * 128);

    int idx[4];
#pragma unroll
    for (int j = 0; j < 4; ++j)
        idx[j] = __builtin_nontemporal_load(g + (r + j * 8));

#pragma unroll
    for (int j = 0; j < 4; ++j) {
        const int nb = r + j * 8;
        if ((unsigned)(idx[j] - lo) < (unsigned)(hi - lo)) {
            const f32x4 v =
                reinterpret_cast<const f32x4*>(feat + (size_t)idx[j] * 128)[c];
            __builtin_nontemporal_store(v - center, &o[(size_t)nb * 32 + c]);
        }
    }
}

extern "C" void kernel_launch(void* const* d_in, const int* in_sizes, int n_in,
                              void* d_out, int out_size, void* d_ws, size_t ws_size,
                              hipStream_t stream) {
    const float* feat  = (const float*)d_in[0];
    const int*   graph = (const int*)d_in[1];
    float*       out   = (float*)d_out;

    const int N = in_sizes[1] / 32;  // x_graph is [1, N, 32]

    ngx_kernel<<<4 * N, 256, 0, stream>>>(feat, graph, out, N);
}

// Round 6
// 108.082 us; speedup vs baseline: 2.0652x; 1.5318x over previous
//
#include <hip/hip_runtime.h>

// Normalized_Graph_expand: out[n, k, :] = feat[g[n,k], :] - feat[n, :]
// B=1, N=25000, F=128, CUT=32.
//
// One block (256 threads) per node (REVERT to round-3 structure — best
// measured, 108 µs):
//   c = tid & 31  -> float4 column group (covers F=128 as 32 x float4)
//   r = tid >> 5  -> neighbor rows r, r+8, r+16, r+24
//
// Traffic model (fits R1/R3/R4/R5 measurements): shared ~6.6 TB/s fabric,
// total bytes = 410 MB writes + ~290 MB gather L2-misses + 16 MB meta
// ≈ 706 MB -> ~107 µs. Structural read-locality schemes (multi-pass R4,
// XCD-sliced R5) both lost: scattered predicated writes + replicated meta
// cost more than the read savings. Contiguous writes win.
//
// - Gather + center + index loads: normal (center/graph allocation helps —
//   the centers ARE the gather table).
// - Output stores: nontemporal (never re-read; keep L2 for the table).
// - All 4 gather loads issued before any store: explicit MLP depth 4.

typedef float f32x4 __attribute__((ext_vector_type(4)));

__global__ __launch_bounds__(256) void ngx_kernel(
    const float* __restrict__ feat,   // [N, 128]
    const int*   __restrict__ graph,  // [N, 32]
    float*       __restrict__ out,    // [N, 32, 128]
    int N)
{
    const int node = blockIdx.x;
    if (node >= N) return;

    const int tid = threadIdx.x;
    const int c = tid & 31;   // float4 column index within a row
    const int r = tid >> 5;   // base neighbor row (0..7)

    const f32x4 center =
        reinterpret_cast<const f32x4*>(feat + (size_t)node * 128)[c];

    const int* g = graph + (size_t)node * 32;
    f32x4* o = reinterpret_cast<f32x4*>(out + (size_t)node * 32 * 128);

    int idx[4];
#pragma unroll
    for (int j = 0; j < 4; ++j)
        idx[j] = g[r + j * 8];

    f32x4 v[4];
#pragma unroll
    for (int j = 0; j < 4; ++j)
        v[j] = reinterpret_cast<const f32x4*>(feat + (size_t)idx[j] * 128)[c];

#pragma unroll
    for (int j = 0; j < 4; ++j)
        __builtin_nontemporal_store(v[j] - center, &o[(size_t)(r + j * 8) * 32 + c]);
}

extern "C" void kernel_launch(void* const* d_in, const int* in_sizes, int n_in,
                              void* d_out, int out_size, void* d_ws, size_t ws_size,
                              hipStream_t stream) {
    const float* feat  = (const float*)d_in[0];
    const int*   graph = (const int*)d_in[1];
    float*       out   = (float*)d_out;

    const int N = in_sizes[1] / 32;  // x_graph is [1, N, 32]

    ngx_kernel<<<N, 256, 0, stream>>>(feat, graph, out, N);
}